// Round 15
// baseline (212.707 us; speedup 1.0000x reference)
//
#include <hip/hip_runtime.h>

// ContinuousNormalizingFlow: B=32768 rows, D=8, H=64, 100 Euler steps.
// R15 = R13 (f16 MFMA frags, zero cross-lane loop, K-perm renames, folded
// scales) with quad-batched reciprocal in tanh: one v_rcp per 4 tanh
// (p = a0a1a2a3, reconstruct 1/ai from partial products). Trans ops drop
// 64 -> 40 per wave-step. R14's magic-seed Newton (packed) mis-behaved on
// HW; this uses only the known-good v_rcp + full-rate muls.

#define TSCALE 2.885390081777926815f // 2*log2(e)

__device__ float g_w1r[64]; // sum_{k<8} W1[j][k]
__device__ float g_w3c[64]; // sum_d W3[d][j]

__global__ void cnf_prep(const float* __restrict__ W1, const float* __restrict__ W3) {
    int h = threadIdx.x; // 64 threads
    float s = 0.f;
#pragma unroll
    for (int k = 0; k < 8; ++k) s += W1[h * 9 + k];
    g_w1r[h] = s;
    float c = 0.f;
#pragma unroll
    for (int d = 0; d < 8; ++d) c += W3[d * 64 + h];
    g_w3c[h] = c;
}

typedef __attribute__((ext_vector_type(8))) _Float16 v8h; // 8 f16 (4 VGPRs)
typedef __attribute__((ext_vector_type(2))) __fp16 v2fp; // cvt_pkrtz result
typedef __attribute__((ext_vector_type(4))) float v4f;   // MFMA C/D
typedef __attribute__((ext_vector_type(2))) float v2f;   // packed fp32 pair

// 4 tanh from PRE-SCALED z (z = 2*log2e*x): th = 1 - 2/(2^z+1), with ONE
// v_rcp for all four: p = (a0a1)(a2a3); 1/ai = rp * (partial products).
// CLAMP: z<=16 keeps p <= 6.6e4^4 = 1.8e19 (th err <= 3e-5, below f16 ulp).
// Unclamped variant is used only where |z| <= ~24 is analytically bounded
// (L2: |W2 row|_1 <= 8, |b2| <= 1/8 -> p <= 2e28 < fp32 max).
__device__ __forceinline__ v4f ftanh4(v4f z, bool clamp) {
    float z0 = z[0], z1 = z[1], z2 = z[2], z3 = z[3];
    if (clamp) {
        z0 = __builtin_fminf(z0, 16.0f);
        z1 = __builtin_fminf(z1, 16.0f);
        z2 = __builtin_fminf(z2, 16.0f);
        z3 = __builtin_fminf(z3, 16.0f);
    }
    float a0 = __builtin_amdgcn_exp2f(z0) + 1.0f;
    float a1 = __builtin_amdgcn_exp2f(z1) + 1.0f;
    float a2 = __builtin_amdgcn_exp2f(z2) + 1.0f;
    float a3 = __builtin_amdgcn_exp2f(z3) + 1.0f;
    float a01 = a0 * a1, a23 = a2 * a3;
    float rp = __builtin_amdgcn_rcpf(a01 * a23);
    float rm = -2.0f * rp;
    float m01 = rm * a23, m23 = rm * a01; // -2/(a0*a1), -2/(a2*a3)
    v4f th;
    th[0] = fmaf(m01, a1, 1.0f);
    th[1] = fmaf(m01, a0, 1.0f);
    th[2] = fmaf(m23, a3, 1.0f);
    th[3] = fmaf(m23, a2, 1.0f);
    return th;
}

union FragU {
    v8h h;
    unsigned u[4];
};

// f16 pair pack: single v_cvt_pkrtz_f16_f32. a -> low half.
__device__ __forceinline__ unsigned pk16(float a, float b) {
    v2fp t = __builtin_amdgcn_cvt_pkrtz(a, b);
    return __builtin_bit_cast(unsigned, t);
}
__device__ __forceinline__ unsigned pk16v(v2f v) { return pk16(v.x, v.y); }

// K-permutation for W2/W3 frags: slot (ks,q,jj) <- physical j.
__device__ __forceinline__ int physj(int ks, int q, int jj) {
    return 16 * (ks + 2 * (jj >> 2)) + 4 * q + (jj & 3);
}

// Rename C-fragment packs (ph[4]: per-mt {r01,r23}) into the B-frag pair.
__device__ __forceinline__ void rename(const uint2 ph[4], FragU bh[2]) {
#pragma unroll
    for (int ks = 0; ks < 2; ++ks) {
        bh[ks].u[0] = ph[ks].x;
        bh[ks].u[1] = ph[ks].y;
        bh[ks].u[2] = ph[ks + 2].x;
        bh[ks].u[3] = ph[ks + 2].y;
    }
}

__global__ __launch_bounds__(256, 2) void cnf_fused(
    const float* __restrict__ x0, const float* __restrict__ W1,
    const float* __restrict__ b1, const float* __restrict__ W2,
    const float* __restrict__ b2, const float* __restrict__ W3,
    const float* __restrict__ b3, const int* __restrict__ nsp,
    float* __restrict__ out, int rows) {
    const int tid = threadIdx.x;
    const int w = tid >> 6;
    const int lane = tid & 63;
    const int c = lane & 15;
    const int q = lane >> 4;
    const int row0 = blockIdx.x * 64 + w * 16;

    const int n = *nsp;
    const float dt = 1.0f / (float)n;

    // ---- A1 (x TSCALE): [x;t;1] layout. q0 jj0-3 = W1[:,0:4], q0 jj4 =
    // W1[:,8] (t), q0 jj5 = b1, q1 jj0-3 = W1[:,4:8], all else 0. ----
    FragU a1[4];
#pragma unroll
    for (int mt = 0; mt < 4; ++mt) {
        const int m = 16 * mt + c;
        float f[8] = {0.f, 0.f, 0.f, 0.f, 0.f, 0.f, 0.f, 0.f};
        if (q == 0) {
#pragma unroll
            for (int jj = 0; jj < 4; ++jj) f[jj] = TSCALE * W1[m * 9 + jj];
            f[4] = TSCALE * W1[m * 9 + 8];
            f[5] = TSCALE * b1[m];
        } else if (q == 1) {
#pragma unroll
            for (int jj = 0; jj < 4; ++jj) f[jj] = TSCALE * W1[m * 9 + 4 + jj];
        }
#pragma unroll
        for (int p = 0; p < 4; ++p) a1[mt].u[p] = pk16(f[2 * p], f[2 * p + 1]);
    }
    // ---- A2 (x TSCALE) K-perm; a2g = w3c[m]*W2*w1r[h]; a2d = W2*(dt*w1t[h]) ----
    FragU a2[4][2], a2g[4][2], a2d[4][2];
#pragma unroll
    for (int mt = 0; mt < 4; ++mt)
#pragma unroll
        for (int ks = 0; ks < 2; ++ks) {
            const int m = 16 * mt + c;
            const float w3cm = g_w3c[m];
            float f[8], fg[8], fd[8];
#pragma unroll
            for (int jj = 0; jj < 8; ++jj) {
                const int pj = physj(ks, q, jj);
                const float wv = W2[m * 64 + pj];
                f[jj] = TSCALE * wv;
                fg[jj] = w3cm * wv * g_w1r[pj];
                fd[jj] = wv * (dt * W1[pj * 9 + 8]);
            }
#pragma unroll
            for (int p = 0; p < 4; ++p) {
                a2[mt][ks].u[p] = pk16(f[2 * p], f[2 * p + 1]);
                a2g[mt][ks].u[p] = pk16(fg[2 * p], fg[2 * p + 1]);
                a2d[mt][ks].u[p] = pk16(fd[2 * p], fd[2 * p + 1]);
            }
        }
    // ---- A3: W3 rows duplicated (m -> m&7), K-permuted ----
    FragU a3[2];
#pragma unroll
    for (int ks = 0; ks < 2; ++ks) {
        float f[8];
#pragma unroll
        for (int jj = 0; jj < 8; ++jj) f[jj] = W3[(c & 7) * 64 + physj(ks, q, jj)];
#pragma unroll
        for (int p = 0; p < 4; ++p) a3[ks].u[p] = pk16(f[2 * p], f[2 * p + 1]);
    }
    // ---- per-lane constants ----
    v4f vb2[4]; // x TSCALE (C-init for scaled z2)
#pragma unroll
    for (int mt = 0; mt < 4; ++mt) {
        const int j0 = 16 * mt + 4 * q;
        vb2[mt][0] = TSCALE * b2[j0]; vb2[mt][1] = TSCALE * b2[j0 + 1];
        vb2[mt][2] = TSCALE * b2[j0 + 2]; vb2[mt][3] = TSCALE * b2[j0 + 3];
    }
    v4f vb3;
#pragma unroll
    for (int r = 0; r < 4; ++r) vb3[r] = b3[(4 * q + r) & 7];

    // ---- x state: ALL lanes hold xr[r] = x[row0+c][(4q+r)&7] (duplicated) ----
    float xr[4];
    {
        float4 v = *(const float4*)(x0 + (size_t)(row0 + c) * 8 + 4 * (q & 1));
        xr[0] = v.x; xr[1] = v.y; xr[2] = v.z; xr[3] = v.w;
    }
    const v4f vzero = {0.f, 0.f, 0.f, 0.f};
    v2f gv = {0.f, 0.f};

    // ================= iteration 0: pure forward at (x0, t=0) =================
    {
        FragU bx;
        bx.u[0] = pk16(xr[0], xr[1]);
        bx.u[1] = pk16(xr[2], xr[3]);
        bx.u[2] = pk16(0.0f, 1.0f);
        bx.u[3] = 0u;
        v4f d1[4];
#pragma unroll
        for (int mt = 0; mt < 4; ++mt)
            d1[mt] = __builtin_amdgcn_mfma_f32_16x16x32_f16(a1[mt].h, bx.h, vzero, 0, 0, 0);
        uint2 ph[4];
#pragma unroll
        for (int mt = 0; mt < 4; ++mt) {
            v4f th = ftanh4(d1[mt], true);
            ph[mt].x = pk16(th[0], th[1]);
            ph[mt].y = pk16(th[2], th[3]);
        }
        FragU bh[2];
        rename(ph, bh);
        v4f d2[4];
#pragma unroll
        for (int mt = 0; mt < 4; ++mt) {
            d2[mt] = __builtin_amdgcn_mfma_f32_16x16x32_f16(a2[mt][0].h, bh[0].h, vb2[mt], 0, 0, 0);
            d2[mt] = __builtin_amdgcn_mfma_f32_16x16x32_f16(a2[mt][1].h, bh[1].h, d2[mt], 0, 0, 0);
        }
#pragma unroll
        for (int mt = 0; mt < 4; ++mt) {
            v4f th = ftanh4(d2[mt], false);
            ph[mt].x = pk16(th[0], th[1]);
            ph[mt].y = pk16(th[2], th[3]);
        }
        FragU bh2[2];
        rename(ph, bh2);
        v4f d3;
        d3 = __builtin_amdgcn_mfma_f32_16x16x32_f16(a3[0].h, bh2[0].h, vb3, 0, 0, 0);
        d3 = __builtin_amdgcn_mfma_f32_16x16x32_f16(a3[1].h, bh2[1].h, d3, 0, 0, 0);
#pragma unroll
        for (int r = 0; r < 4; ++r) xr[r] = fmaf(dt, d3[r], xr[r]);
    }

    // ====== iterations i = 1..n-1: bwd(i-1) + fwd(i) from one L1 eval ======
    float tp = 0.0f; // t_{i-1}
    for (int i = 1; i < n; ++i) {
        FragU bx; // [x_i; t_{i-1}; 1]
        bx.u[0] = pk16(xr[0], xr[1]);
        bx.u[1] = pk16(xr[2], xr[3]);
        bx.u[2] = pk16(tp, 1.0f);
        bx.u[3] = 0u;
        tp += dt;
        v4f d1[4];
#pragma unroll
        for (int mt = 0; mt < 4; ++mt)
            d1[mt] = __builtin_amdgcn_mfma_f32_16x16x32_f16(a1[mt].h, bx.h, vzero, 0, 0, 0);

        // th1b = tanh(z1 @ t_{i-1}); om1 = 1 - th1b^2 (packed math)
        uint2 phb[4], pom[4];
#pragma unroll
        for (int mt = 0; mt < 4; ++mt) {
            v4f th = ftanh4(d1[mt], true);
            v2f th01 = {th[0], th[1]}, th23 = {th[2], th[3]};
            v2f om01 = v2f{1.f, 1.f} - th01 * th01;
            v2f om23 = v2f{1.f, 1.f} - th23 * th23;
            phb[mt].x = pk16v(th01);
            phb[mt].y = pk16v(th23);
            pom[mt].x = pk16v(om01);
            pom[mt].y = pk16v(om23);
        }
        FragU bhb[2], bo[2];
        rename(phb, bhb);
        rename(pom, bo);

        v4f z2b[4], sg[4], dz2[4];
#pragma unroll
        for (int mt = 0; mt < 4; ++mt) {
            z2b[mt] = __builtin_amdgcn_mfma_f32_16x16x32_f16(a2[mt][0].h, bhb[0].h, vb2[mt], 0, 0, 0);
            z2b[mt] = __builtin_amdgcn_mfma_f32_16x16x32_f16(a2[mt][1].h, bhb[1].h, z2b[mt], 0, 0, 0);
            sg[mt] = __builtin_amdgcn_mfma_f32_16x16x32_f16(a2g[mt][0].h, bo[0].h, vzero, 0, 0, 0);
            sg[mt] = __builtin_amdgcn_mfma_f32_16x16x32_f16(a2g[mt][1].h, bo[1].h, sg[mt], 0, 0, 0);
            dz2[mt] = __builtin_amdgcn_mfma_f32_16x16x32_f16(a2d[mt][0].h, bo[0].h, vzero, 0, 0, 0);
            dz2[mt] = __builtin_amdgcn_mfma_f32_16x16x32_f16(a2d[mt][1].h, bo[1].h, dz2[mt], 0, 0, 0);
        }

        // th2b = tanh(z2b). g += om2*sg (w3c pre-folded). th2f = th2b+om2*dz2.
        uint2 ph2[4];
#pragma unroll
        for (int mt = 0; mt < 4; ++mt) {
            v4f th = ftanh4(z2b[mt], false);
            v2f th01 = {th[0], th[1]}, th23 = {th[2], th[3]};
            v2f om01 = v2f{1.f, 1.f} - th01 * th01;
            v2f om23 = v2f{1.f, 1.f} - th23 * th23;
            gv += om01 * v2f{sg[mt][0], sg[mt][1]};
            gv += om23 * v2f{sg[mt][2], sg[mt][3]};
            v2f tf01 = om01 * v2f{dz2[mt][0], dz2[mt][1]} + th01;
            v2f tf23 = om23 * v2f{dz2[mt][2], dz2[mt][3]} + th23;
            ph2[mt].x = pk16v(tf01);
            ph2[mt].y = pk16v(tf23);
        }
        FragU bh2[2];
        rename(ph2, bh2);
        v4f d3;
        d3 = __builtin_amdgcn_mfma_f32_16x16x32_f16(a3[0].h, bh2[0].h, vb3, 0, 0, 0);
        d3 = __builtin_amdgcn_mfma_f32_16x16x32_f16(a3[1].h, bh2[1].h, d3, 0, 0, 0);
#pragma unroll
        for (int r = 0; r < 4; ++r) xr[r] = fmaf(dt, d3[r], xr[r]);
    }

    // ============ final bwd at (x_n, t_{n-1}) ============
    {
        FragU bx;
        bx.u[0] = pk16(xr[0], xr[1]);
        bx.u[1] = pk16(xr[2], xr[3]);
        bx.u[2] = pk16(tp, 1.0f); // tp == (n-1)*dt
        bx.u[3] = 0u;
        v4f d1[4];
#pragma unroll
        for (int mt = 0; mt < 4; ++mt)
            d1[mt] = __builtin_amdgcn_mfma_f32_16x16x32_f16(a1[mt].h, bx.h, vzero, 0, 0, 0);
        uint2 phb[4], pom[4];
#pragma unroll
        for (int mt = 0; mt < 4; ++mt) {
            v4f th = ftanh4(d1[mt], true);
            v2f th01 = {th[0], th[1]}, th23 = {th[2], th[3]};
            v2f om01 = v2f{1.f, 1.f} - th01 * th01;
            v2f om23 = v2f{1.f, 1.f} - th23 * th23;
            phb[mt].x = pk16v(th01);
            phb[mt].y = pk16v(th23);
            pom[mt].x = pk16v(om01);
            pom[mt].y = pk16v(om23);
        }
        FragU bhb[2], bo[2];
        rename(phb, bhb);
        rename(pom, bo);
        v4f z2b[4], sg[4];
#pragma unroll
        for (int mt = 0; mt < 4; ++mt) {
            z2b[mt] = __builtin_amdgcn_mfma_f32_16x16x32_f16(a2[mt][0].h, bhb[0].h, vb2[mt], 0, 0, 0);
            z2b[mt] = __builtin_amdgcn_mfma_f32_16x16x32_f16(a2[mt][1].h, bhb[1].h, z2b[mt], 0, 0, 0);
            sg[mt] = __builtin_amdgcn_mfma_f32_16x16x32_f16(a2g[mt][0].h, bo[0].h, vzero, 0, 0, 0);
            sg[mt] = __builtin_amdgcn_mfma_f32_16x16x32_f16(a2g[mt][1].h, bo[1].h, sg[mt], 0, 0, 0);
        }
#pragma unroll
        for (int mt = 0; mt < 4; ++mt) {
            v4f th = ftanh4(z2b[mt], false);
            v2f th01 = {th[0], th[1]}, th23 = {th[2], th[3]};
            v2f om01 = v2f{1.f, 1.f} - th01 * th01;
            v2f om23 = v2f{1.f, 1.f} - th23 * th23;
            gv += om01 * v2f{sg[mt][0], sg[mt][1]};
            gv += om23 * v2f{sg[mt][2], sg[mt][3]};
        }
    }

    // ---- epilogue ----
    float g = gv.x + gv.y;
    g += __shfl_xor(g, 16);
    g += __shfl_xor(g, 32);
    if (q < 2) {
        float4 st = {xr[0], xr[1], xr[2], xr[3]};
        *(float4*)(out + (size_t)(row0 + c) * 8 + 4 * q) = st;
    }
    if (q == 0) out[(size_t)rows * 8 + row0 + c] = dt * g;
}

extern "C" void kernel_launch(void* const* d_in, const int* in_sizes, int n_in,
                              void* d_out, int out_size, void* d_ws, size_t ws_size,
                              hipStream_t stream) {
    const float* x0 = (const float*)d_in[0];
    const float* W1 = (const float*)d_in[1];
    const float* b1 = (const float*)d_in[2];
    const float* W2 = (const float*)d_in[3];
    const float* b2 = (const float*)d_in[4];
    const float* W3 = (const float*)d_in[5];
    const float* b3 = (const float*)d_in[6];
    const int* ns = (const int*)d_in[7];
    float* out = (float*)d_out;
    const int rows = in_sizes[0] / 8; // 32768

    hipLaunchKernelGGL(cnf_prep, dim3(1), dim3(64), 0, stream, W1, W3);
    hipLaunchKernelGGL(cnf_fused, dim3(rows / 64), dim3(256), 0, stream,
                       x0, W1, b1, W2, b2, W3, b3, ns, out, rows);
}

// Round 16
// 202.410 us; speedup vs baseline: 1.0509x; 1.0509x over previous
//
#include <hip/hip_runtime.h>

// ContinuousNormalizingFlow: B=32768 rows, D=8, H=64, 100 Euler steps.
// R16 = R13's step loop exactly (163 us verified: f16 MFMA frags, zero
// cross-lane loop, K-perm renames, folded scales, plain exp+rcp tanh —
// R14/R15 proved trans ops issue near full rate, so that tanh is optimal)
// with cnf_prep folded into the kernel setup (w1r/w3c computed inline from
// L2-broadcast loads) -> single kernel, one less dispatch in the graph.

#define TSCALE 2.885390081777926815f // 2*log2(e)

// tanh from PRE-SCALED z (z = 2*log2e*x): 1 - 2/(2^z + 1). inf-safe.
__device__ __forceinline__ float ftanh_s(float z) {
    float e = __builtin_amdgcn_exp2f(z);
    float r = __builtin_amdgcn_rcpf(e + 1.0f);
    return fmaf(-2.0f, r, 1.0f);
}

typedef __attribute__((ext_vector_type(8))) _Float16 v8h; // 8 f16 (4 VGPRs)
typedef __attribute__((ext_vector_type(2))) __fp16 v2fp; // cvt_pkrtz result
typedef __attribute__((ext_vector_type(4))) float v4f;   // MFMA C/D
typedef __attribute__((ext_vector_type(2))) float v2f;   // packed fp32 pair

union FragU {
    v8h h;
    unsigned u[4];
};

// f16 pair pack: single v_cvt_pkrtz_f16_f32. a -> low half.
__device__ __forceinline__ unsigned pk16(float a, float b) {
    v2fp t = __builtin_amdgcn_cvt_pkrtz(a, b);
    return __builtin_bit_cast(unsigned, t);
}
__device__ __forceinline__ unsigned pk16v(v2f v) { return pk16(v.x, v.y); }

// K-permutation for W2/W3 frags: slot (ks,q,jj) <- physical j.
__device__ __forceinline__ int physj(int ks, int q, int jj) {
    return 16 * (ks + 2 * (jj >> 2)) + 4 * q + (jj & 3);
}

// Rename C-fragment packs (ph[4]: per-mt {r01,r23}) into the B-frag pair.
__device__ __forceinline__ void rename(const uint2 ph[4], FragU bh[2]) {
#pragma unroll
    for (int ks = 0; ks < 2; ++ks) {
        bh[ks].u[0] = ph[ks].x;
        bh[ks].u[1] = ph[ks].y;
        bh[ks].u[2] = ph[ks + 2].x;
        bh[ks].u[3] = ph[ks + 2].y;
    }
}

__global__ __launch_bounds__(256, 2) void cnf_fused(
    const float* __restrict__ x0, const float* __restrict__ W1,
    const float* __restrict__ b1, const float* __restrict__ W2,
    const float* __restrict__ b2, const float* __restrict__ W3,
    const float* __restrict__ b3, const int* __restrict__ nsp,
    float* __restrict__ out, int rows) {
    const int tid = threadIdx.x;
    const int w = tid >> 6;
    const int lane = tid & 63;
    const int c = lane & 15;
    const int q = lane >> 4;
    const int row0 = blockIdx.x * 64 + w * 16;

    const int n = *nsp;
    const float dt = 1.0f / (float)n;

    // ---- A1 (x TSCALE): [x;t;1] layout. q0 jj0-3 = W1[:,0:4], q0 jj4 =
    // W1[:,8] (t), q0 jj5 = b1, q1 jj0-3 = W1[:,4:8], all else 0. ----
    FragU a1[4];
#pragma unroll
    for (int mt = 0; mt < 4; ++mt) {
        const int m = 16 * mt + c;
        float f[8] = {0.f, 0.f, 0.f, 0.f, 0.f, 0.f, 0.f, 0.f};
        if (q == 0) {
#pragma unroll
            for (int jj = 0; jj < 4; ++jj) f[jj] = TSCALE * W1[m * 9 + jj];
            f[4] = TSCALE * W1[m * 9 + 8];
            f[5] = TSCALE * b1[m];
        } else if (q == 1) {
#pragma unroll
            for (int jj = 0; jj < 4; ++jj) f[jj] = TSCALE * W1[m * 9 + 4 + jj];
        }
#pragma unroll
        for (int p = 0; p < 4; ++p) a1[mt].u[p] = pk16(f[2 * p], f[2 * p + 1]);
    }
    // ---- A2 (x TSCALE) K-perm; a2g = w3c[m]*W2*w1r[h]; a2d = W2*(dt*w1t[h]).
    // w1r[h] = sum_k W1[h][0:8]; w3c[m] = sum_d W3[d][m] — computed inline
    // (L2-broadcast loads; prep kernel eliminated). ----
    FragU a2[4][2], a2g[4][2], a2d[4][2];
#pragma unroll
    for (int mt = 0; mt < 4; ++mt) {
        const int m = 16 * mt + c;
        float w3cm = 0.f;
#pragma unroll
        for (int d = 0; d < 8; ++d) w3cm += W3[d * 64 + m];
#pragma unroll
        for (int ks = 0; ks < 2; ++ks) {
            float f[8], fg[8], fd[8];
#pragma unroll
            for (int jj = 0; jj < 8; ++jj) {
                const int pj = physj(ks, q, jj);
                const float wv = W2[m * 64 + pj];
                float w1r = 0.f;
#pragma unroll
                for (int k = 0; k < 8; ++k) w1r += W1[pj * 9 + k];
                f[jj] = TSCALE * wv;
                fg[jj] = w3cm * wv * w1r;
                fd[jj] = wv * (dt * W1[pj * 9 + 8]);
            }
#pragma unroll
            for (int p = 0; p < 4; ++p) {
                a2[mt][ks].u[p] = pk16(f[2 * p], f[2 * p + 1]);
                a2g[mt][ks].u[p] = pk16(fg[2 * p], fg[2 * p + 1]);
                a2d[mt][ks].u[p] = pk16(fd[2 * p], fd[2 * p + 1]);
            }
        }
    }
    // ---- A3: W3 rows duplicated (m -> m&7), K-permuted ----
    FragU a3[2];
#pragma unroll
    for (int ks = 0; ks < 2; ++ks) {
        float f[8];
#pragma unroll
        for (int jj = 0; jj < 8; ++jj) f[jj] = W3[(c & 7) * 64 + physj(ks, q, jj)];
#pragma unroll
        for (int p = 0; p < 4; ++p) a3[ks].u[p] = pk16(f[2 * p], f[2 * p + 1]);
    }
    // ---- per-lane constants ----
    v4f vb2[4]; // x TSCALE (C-init for scaled z2)
#pragma unroll
    for (int mt = 0; mt < 4; ++mt) {
        const int j0 = 16 * mt + 4 * q;
        vb2[mt][0] = TSCALE * b2[j0]; vb2[mt][1] = TSCALE * b2[j0 + 1];
        vb2[mt][2] = TSCALE * b2[j0 + 2]; vb2[mt][3] = TSCALE * b2[j0 + 3];
    }
    v4f vb3;
#pragma unroll
    for (int r = 0; r < 4; ++r) vb3[r] = b3[(4 * q + r) & 7];

    // ---- x state: ALL lanes hold xr[r] = x[row0+c][(4q+r)&7] (duplicated) ----
    float xr[4];
    {
        float4 v = *(const float4*)(x0 + (size_t)(row0 + c) * 8 + 4 * (q & 1));
        xr[0] = v.x; xr[1] = v.y; xr[2] = v.z; xr[3] = v.w;
    }
    const v4f vzero = {0.f, 0.f, 0.f, 0.f};
    v2f gv = {0.f, 0.f};

    // ================= iteration 0: pure forward at (x0, t=0) =================
    {
        FragU bx;
        bx.u[0] = pk16(xr[0], xr[1]);
        bx.u[1] = pk16(xr[2], xr[3]);
        bx.u[2] = pk16(0.0f, 1.0f);
        bx.u[3] = 0u;
        v4f d1[4];
#pragma unroll
        for (int mt = 0; mt < 4; ++mt)
            d1[mt] = __builtin_amdgcn_mfma_f32_16x16x32_f16(a1[mt].h, bx.h, vzero, 0, 0, 0);
        uint2 ph[4];
#pragma unroll
        for (int mt = 0; mt < 4; ++mt) {
            ph[mt].x = pk16(ftanh_s(d1[mt][0]), ftanh_s(d1[mt][1]));
            ph[mt].y = pk16(ftanh_s(d1[mt][2]), ftanh_s(d1[mt][3]));
        }
        FragU bh[2];
        rename(ph, bh);
        v4f d2[4];
#pragma unroll
        for (int mt = 0; mt < 4; ++mt) {
            d2[mt] = __builtin_amdgcn_mfma_f32_16x16x32_f16(a2[mt][0].h, bh[0].h, vb2[mt], 0, 0, 0);
            d2[mt] = __builtin_amdgcn_mfma_f32_16x16x32_f16(a2[mt][1].h, bh[1].h, d2[mt], 0, 0, 0);
        }
#pragma unroll
        for (int mt = 0; mt < 4; ++mt) {
            ph[mt].x = pk16(ftanh_s(d2[mt][0]), ftanh_s(d2[mt][1]));
            ph[mt].y = pk16(ftanh_s(d2[mt][2]), ftanh_s(d2[mt][3]));
        }
        FragU bh2[2];
        rename(ph, bh2);
        v4f d3;
        d3 = __builtin_amdgcn_mfma_f32_16x16x32_f16(a3[0].h, bh2[0].h, vb3, 0, 0, 0);
        d3 = __builtin_amdgcn_mfma_f32_16x16x32_f16(a3[1].h, bh2[1].h, d3, 0, 0, 0);
#pragma unroll
        for (int r = 0; r < 4; ++r) xr[r] = fmaf(dt, d3[r], xr[r]);
    }

    // ====== iterations i = 1..n-1: bwd(i-1) + fwd(i) from one L1 eval ======
    float tp = 0.0f; // t_{i-1}
    for (int i = 1; i < n; ++i) {
        FragU bx; // [x_i; t_{i-1}; 1]
        bx.u[0] = pk16(xr[0], xr[1]);
        bx.u[1] = pk16(xr[2], xr[3]);
        bx.u[2] = pk16(tp, 1.0f);
        bx.u[3] = 0u;
        tp += dt;
        v4f d1[4];
#pragma unroll
        for (int mt = 0; mt < 4; ++mt)
            d1[mt] = __builtin_amdgcn_mfma_f32_16x16x32_f16(a1[mt].h, bx.h, vzero, 0, 0, 0);

        // th1b = tanh(z1 @ t_{i-1}); om1 = 1 - th1b^2 (packed math)
        uint2 phb[4], pom[4];
#pragma unroll
        for (int mt = 0; mt < 4; ++mt) {
            v2f th01 = {ftanh_s(d1[mt][0]), ftanh_s(d1[mt][1])};
            v2f th23 = {ftanh_s(d1[mt][2]), ftanh_s(d1[mt][3])};
            v2f om01 = v2f{1.f, 1.f} - th01 * th01;
            v2f om23 = v2f{1.f, 1.f} - th23 * th23;
            phb[mt].x = pk16v(th01);
            phb[mt].y = pk16v(th23);
            pom[mt].x = pk16v(om01);
            pom[mt].y = pk16v(om23);
        }
        FragU bhb[2], bo[2];
        rename(phb, bhb);
        rename(pom, bo);

        v4f z2b[4], sg[4], dz2[4];
#pragma unroll
        for (int mt = 0; mt < 4; ++mt) {
            z2b[mt] = __builtin_amdgcn_mfma_f32_16x16x32_f16(a2[mt][0].h, bhb[0].h, vb2[mt], 0, 0, 0);
            z2b[mt] = __builtin_amdgcn_mfma_f32_16x16x32_f16(a2[mt][1].h, bhb[1].h, z2b[mt], 0, 0, 0);
            sg[mt] = __builtin_amdgcn_mfma_f32_16x16x32_f16(a2g[mt][0].h, bo[0].h, vzero, 0, 0, 0);
            sg[mt] = __builtin_amdgcn_mfma_f32_16x16x32_f16(a2g[mt][1].h, bo[1].h, sg[mt], 0, 0, 0);
            dz2[mt] = __builtin_amdgcn_mfma_f32_16x16x32_f16(a2d[mt][0].h, bo[0].h, vzero, 0, 0, 0);
            dz2[mt] = __builtin_amdgcn_mfma_f32_16x16x32_f16(a2d[mt][1].h, bo[1].h, dz2[mt], 0, 0, 0);
        }

        // th2b = tanh(z2b). g += om2*sg (w3c pre-folded). th2f = th2b+om2*dz2.
        uint2 ph2[4];
#pragma unroll
        for (int mt = 0; mt < 4; ++mt) {
            v2f th01 = {ftanh_s(z2b[mt][0]), ftanh_s(z2b[mt][1])};
            v2f th23 = {ftanh_s(z2b[mt][2]), ftanh_s(z2b[mt][3])};
            v2f om01 = v2f{1.f, 1.f} - th01 * th01;
            v2f om23 = v2f{1.f, 1.f} - th23 * th23;
            gv += om01 * v2f{sg[mt][0], sg[mt][1]};
            gv += om23 * v2f{sg[mt][2], sg[mt][3]};
            v2f tf01 = om01 * v2f{dz2[mt][0], dz2[mt][1]} + th01;
            v2f tf23 = om23 * v2f{dz2[mt][2], dz2[mt][3]} + th23;
            ph2[mt].x = pk16v(tf01);
            ph2[mt].y = pk16v(tf23);
        }
        FragU bh2[2];
        rename(ph2, bh2);
        v4f d3;
        d3 = __builtin_amdgcn_mfma_f32_16x16x32_f16(a3[0].h, bh2[0].h, vb3, 0, 0, 0);
        d3 = __builtin_amdgcn_mfma_f32_16x16x32_f16(a3[1].h, bh2[1].h, d3, 0, 0, 0);
#pragma unroll
        for (int r = 0; r < 4; ++r) xr[r] = fmaf(dt, d3[r], xr[r]);
    }

    // ============ final bwd at (x_n, t_{n-1}) ============
    {
        FragU bx;
        bx.u[0] = pk16(xr[0], xr[1]);
        bx.u[1] = pk16(xr[2], xr[3]);
        bx.u[2] = pk16(tp, 1.0f); // tp == (n-1)*dt
        bx.u[3] = 0u;
        v4f d1[4];
#pragma unroll
        for (int mt = 0; mt < 4; ++mt)
            d1[mt] = __builtin_amdgcn_mfma_f32_16x16x32_f16(a1[mt].h, bx.h, vzero, 0, 0, 0);
        uint2 phb[4], pom[4];
#pragma unroll
        for (int mt = 0; mt < 4; ++mt) {
            v2f th01 = {ftanh_s(d1[mt][0]), ftanh_s(d1[mt][1])};
            v2f th23 = {ftanh_s(d1[mt][2]), ftanh_s(d1[mt][3])};
            v2f om01 = v2f{1.f, 1.f} - th01 * th01;
            v2f om23 = v2f{1.f, 1.f} - th23 * th23;
            phb[mt].x = pk16v(th01);
            phb[mt].y = pk16v(th23);
            pom[mt].x = pk16v(om01);
            pom[mt].y = pk16v(om23);
        }
        FragU bhb[2], bo[2];
        rename(phb, bhb);
        rename(pom, bo);
        v4f z2b[4], sg[4];
#pragma unroll
        for (int mt = 0; mt < 4; ++mt) {
            z2b[mt] = __builtin_amdgcn_mfma_f32_16x16x32_f16(a2[mt][0].h, bhb[0].h, vb2[mt], 0, 0, 0);
            z2b[mt] = __builtin_amdgcn_mfma_f32_16x16x32_f16(a2[mt][1].h, bhb[1].h, z2b[mt], 0, 0, 0);
            sg[mt] = __builtin_amdgcn_mfma_f32_16x16x32_f16(a2g[mt][0].h, bo[0].h, vzero, 0, 0, 0);
            sg[mt] = __builtin_amdgcn_mfma_f32_16x16x32_f16(a2g[mt][1].h, bo[1].h, sg[mt], 0, 0, 0);
        }
#pragma unroll
        for (int mt = 0; mt < 4; ++mt) {
            v2f th01 = {ftanh_s(z2b[mt][0]), ftanh_s(z2b[mt][1])};
            v2f th23 = {ftanh_s(z2b[mt][2]), ftanh_s(z2b[mt][3])};
            v2f om01 = v2f{1.f, 1.f} - th01 * th01;
            v2f om23 = v2f{1.f, 1.f} - th23 * th23;
            gv += om01 * v2f{sg[mt][0], sg[mt][1]};
            gv += om23 * v2f{sg[mt][2], sg[mt][3]};
        }
    }

    // ---- epilogue ----
    float g = gv.x + gv.y;
    g += __shfl_xor(g, 16);
    g += __shfl_xor(g, 32);
    if (q < 2) {
        float4 st = {xr[0], xr[1], xr[2], xr[3]};
        *(float4*)(out + (size_t)(row0 + c) * 8 + 4 * q) = st;
    }
    if (q == 0) out[(size_t)rows * 8 + row0 + c] = dt * g;
}

extern "C" void kernel_launch(void* const* d_in, const int* in_sizes, int n_in,
                              void* d_out, int out_size, void* d_ws, size_t ws_size,
                              hipStream_t stream) {
    const float* x0 = (const float*)d_in[0];
    const float* W1 = (const float*)d_in[1];
    const float* b1 = (const float*)d_in[2];
    const float* W2 = (const float*)d_in[3];
    const float* b2 = (const float*)d_in[4];
    const float* W3 = (const float*)d_in[5];
    const float* b3 = (const float*)d_in[6];
    const int* ns = (const int*)d_in[7];
    float* out = (float*)d_out;
    const int rows = in_sizes[0] / 8; // 32768

    hipLaunchKernelGGL(cnf_fused, dim3(rows / 64), dim3(256), 0, stream,
                       x0, W1, b1, W2, b2, W3, b3, ns, out, rows);
}